// Round 4
// baseline (248.688 us; speedup 1.0000x reference)
//
#include <hip/hip_runtime.h>

// Problem constants
#define NB 16
#define NH 96
#define NW 320
#define NCIN 32

#define FC_K 61440
#define FC_KB 64           // k per block (2 phases x 32)
#define FC_NKC 960         // 61440/64 chunks = grid; 3.75 blocks/CU avg

typedef __attribute__((ext_vector_type(8))) short short8;     // 8 bf16 (4 VGPRs)
typedef __attribute__((ext_vector_type(4))) float f32x4;

__device__ inline unsigned short f2bf(float f) {
    union { float f; unsigned int u; } v; v.f = f;
    unsigned int r = v.u + 0x7FFF + ((v.u >> 16) & 1);   // RNE
    return (unsigned short)(r >> 16);
}

// ---------------------------------------------------------------------------
// Fused setup kernel.
// Blocks [0,396): weight fragments OIHW fp32 -> MFMA B-operand bf16,
//   wf[((kk*NT + nt)*64 + lane)*8 + j], oc = nt*16+(lane&15),
//   ic = ks*32+(lane>>4)*8+j  [m91-verified map]
// Blocks [396,...): scatter+cast active cells from fp32 input into the
//   (memset-zeroed) dense bf16 input. Reads ONLY active cells (~25.6 MB).
//   4 threads per coord, 8 ch each; duplicates write identical bytes.
// ---------------------------------------------------------------------------
__global__ __launch_bounds__(256) void setup_all(const float* __restrict__ w1,
                                                 const float* __restrict__ w2,
                                                 const float* __restrict__ w3,
                                                 unsigned short* __restrict__ f1,
                                                 unsigned short* __restrict__ f2,
                                                 unsigned short* __restrict__ f3,
                                                 const int* __restrict__ coords,
                                                 const float* __restrict__ input,
                                                 unsigned short* __restrict__ inBf,
                                                 int n) {
    if (blockIdx.x < 396) {
        int i = blockIdx.x * 256 + threadIdx.x;
        if (i < 9216) {                       // conv1: IC=32 OC=32 NT=2 KS=1
            int j = i & 7, lane = (i >> 3) & 63, nt = (i >> 9) & 1, tap = i >> 10;
            int ic = ((lane >> 4) * 8) + j, oc = nt * 16 + (lane & 15);
            f1[i] = f2bf(w1[(oc * 32 + ic) * 9 + tap]);
        } else if (i < 27648) {               // conv2: IC=32 OC=64 NT=4 KS=1
            int v = i - 9216;
            int j = v & 7, lane = (v >> 3) & 63, nt = (v >> 9) & 3, tap = v >> 11;
            int ic = ((lane >> 4) * 8) + j, oc = nt * 16 + (lane & 15);
            f2[v] = f2bf(w2[(oc * 32 + ic) * 9 + tap]);
        } else if (i < 101376) {              // conv3: IC=64 OC=128 NT=8 KS=2
            int v = i - 27648;
            int j = v & 7, lane = (v >> 3) & 63, nt = (v >> 9) & 7, kk = v >> 12;
            int tap = kk >> 1, ks = kk & 1;
            int ic = ks * 32 + ((lane >> 4) * 8) + j, oc = nt * 16 + (lane & 15);
            f3[v] = f2bf(w3[(oc * 64 + ic) * 9 + tap]);
        }
    } else {
        int i = (blockIdx.x - 396) * 256 + threadIdx.x;
        if (i >= n * 4) return;
        int ci = i >> 2, q = i & 3;
        int b = coords[ci * 3 + 0], y = coords[ci * 3 + 1], x = coords[ci * 3 + 2];
        long base = ((long)((b * NH + y) * NW + x)) * NCIN + q * 8;
        const float4* src = (const float4*)(input + base);
        float4 v0 = src[0], v1 = src[1];
        union { short8 s8; unsigned short us[8]; } o;
        o.us[0] = f2bf(v0.x); o.us[1] = f2bf(v0.y); o.us[2] = f2bf(v0.z); o.us[3] = f2bf(v0.w);
        o.us[4] = f2bf(v1.x); o.us[5] = f2bf(v1.y); o.us[6] = f2bf(v1.z); o.us[7] = f2bf(v1.w);
        *(short8*)(inBf + base) = o.s8;
    }
}

// ---------------------------------------------------------------------------
// Implicit-GEMM conv 3x3 stride-2 pad-1 via bf16 MFMA (16x16x32), bf16 NHWC in.
// Each wave: one 16-position strip x NL oc-tiles. A-fragments loaded ONCE
// per ks (9 x 16 B/lane, unconditional, addr clamped to cell 0, reg-reg
// cndmask -- R8 lesson), reused for NL*9 MFMAs (R9/R10 lesson: oc-tile
// duplication of the scattered gather was the stall). B-frag loads coalesced
// 1KB/wave, L1-hot, in-loop. acc indices compile-time (R4), ks loop unroll 1
// (R2). Layouts m89/m91: A[m=lane&15][k=quad*8+j], D[row=quad*4+reg][col=lane&15].
// ---------------------------------------------------------------------------
template<int IC, int OC, int NL, int IH, int IW, int OH, int OW>
__global__ __launch_bounds__(256) void conv_mfma(
    const unsigned short* __restrict__ inPtr,  // NHWC bf16
    const unsigned short* __restrict__ wfrag,  // B-fragments bf16
    const float* __restrict__ bias,
    float* __restrict__ out)                   // NHWC fp32 (pre-relu)
{
    constexpr int KS = IC / 32;
    constexpr int NT = OC / 16;
    constexpr int NG = NT / NL;                // wave-groups per strip
    constexpr int NSTRIPS = NB * OH * OW / 16;

    const int wid  = (blockIdx.x * 256 + threadIdx.x) >> 6;
    const int lane = threadIdx.x & 63;
    const int ntb  = (wid % NG) * NL;
    const int s    = wid / NG;
    if (s >= NSTRIPS) return;
    const int quad = lane >> 4;
    const int lm   = lane & 15;

    const int p0 = s * 16;
    const int posA = p0 + lm;
    const int b  = posA / (OH * OW);
    const int rr = posA % (OH * OW);
    const int oy = rr / OW, ox = rr % OW;
    const int iy0 = oy * 2 - 1, ix0 = ox * 2 - 1;

    int cell[9];
    bool okb[9];
    #pragma unroll
    for (int t9 = 0; t9 < 9; t9++) {
        const int iy = iy0 + t9 / 3;
        const int ix = ix0 + t9 % 3;
        const bool ok = (iy >= 0) && (iy < IH) && (ix >= 0) && (ix < IW);
        cell[t9] = ok ? ((b * IH + iy) * IW + ix) : 0;   // clamp addr, not load
        okb[t9] = ok;
    }

    short8 zero8;
    #pragma unroll
    for (int j = 0; j < 8; j++) zero8[j] = 0;

    f32x4 acc[NL][2];
    #pragma unroll
    for (int nl = 0; nl < NL; nl++)
        #pragma unroll
        for (int pp = 0; pp < 2; pp++)
            acc[nl][pp] = (f32x4){0.f, 0.f, 0.f, 0.f};

    #pragma unroll 1
    for (int ks = 0; ks < KS; ks++) {
        short8 av[9];
        #pragma unroll
        for (int t9 = 0; t9 < 9; t9++) {
            short8 v = *(const short8*)(inPtr + (long)cell[t9] * IC + ks * 32 + quad * 8);
            av[t9] = okb[t9] ? v : zero8;      // reg-reg cndmask
        }
        #pragma unroll
        for (int nl = 0; nl < NL; nl++) {
            #pragma unroll
            for (int t9 = 0; t9 < 9; t9++) {
                short8 bf = *(const short8*)(wfrag + (((t9 * KS + ks) * NT + ntb + nl) * 64 + lane) * 8);
                if (t9 & 1) acc[nl][1] = __builtin_amdgcn_mfma_f32_16x16x32_bf16(av[t9], bf, acc[nl][1], 0, 0, 0);
                else        acc[nl][0] = __builtin_amdgcn_mfma_f32_16x16x32_bf16(av[t9], bf, acc[nl][0], 0, 0, 0);
            }
        }
    }

    const long rowBase = (long)p0 + quad * 4;   // D: row=(lane>>4)*4+reg
    #pragma unroll
    for (int nl = 0; nl < NL; nl++) {
        const int oc = (ntb + nl) * 16 + lm;
        const float bv = bias[oc];
        #pragma unroll
        for (int reg = 0; reg < 4; reg++)
            out[(rowBase + reg) * OC + oc] = acc[nl][0][reg] + acc[nl][1][reg] + bv;
    }
}

// ---------------------------------------------------------------------------
// 3x3 stride-1 pad-1 maxpool (-inf pad) + ReLU, NHWC. fp32 in; bf16 or fp32
// out (bf16 feeds the next conv's MFMA A-operand).
// ---------------------------------------------------------------------------
template<int C, int HH, int WW, bool BF16OUT>
__global__ __launch_bounds__(256) void maxpool3_relu(const float* __restrict__ in, void* __restrict__ outv) {
    constexpr int C4 = C / 4;
    int i = blockIdx.x * blockDim.x + threadIdx.x;
    if (i >= NB * HH * WW * C4) return;
    int c = i % C4;
    int x = (i / C4) % WW;
    int y = (i / (C4 * WW)) % HH;
    int b = i / (C4 * WW * HH);
    float4 m = make_float4(-3.0e38f, -3.0e38f, -3.0e38f, -3.0e38f);
    #pragma unroll
    for (int dy = -1; dy <= 1; dy++) {
        int yy = y + dy;
        if (yy < 0 || yy >= HH) continue;
        #pragma unroll
        for (int dx = -1; dx <= 1; dx++) {
            int xx = x + dx;
            if (xx < 0 || xx >= WW) continue;
            float4 v = ((const float4*)in)[((b * HH + yy) * WW + xx) * C4 + c];
            m.x = fmaxf(m.x, v.x);
            m.y = fmaxf(m.y, v.y);
            m.z = fmaxf(m.z, v.z);
            m.w = fmaxf(m.w, v.w);
        }
    }
    m.x = fmaxf(m.x, 0.f);
    m.y = fmaxf(m.y, 0.f);
    m.z = fmaxf(m.z, 0.f);
    m.w = fmaxf(m.w, 0.f);
    if (BF16OUT) {
        ushort4 o;
        o.x = f2bf(m.x); o.y = f2bf(m.y); o.z = f2bf(m.z); o.w = f2bf(m.w);
        ((ushort4*)outv)[i] = o;
    } else {
        ((float4*)outv)[i] = m;
    }
}

// ---------------------------------------------------------------------------
// LDS-tiled permute: in[b][pos][c] (NHWC pooled3 fp32, pos=480,c=128) ->
// xT[c*480+pos][b]. Both sides coalesced float4.
// ---------------------------------------------------------------------------
__global__ __launch_bounds__(256) void transpose_fc(const float* __restrict__ in, float* __restrict__ xT) {
    __shared__ float tile_s[32 * 16 * 17];    // [c_l][pos_l][b(pad 17)]
    const int pt = blockIdx.x % 30;
    const int ct = blockIdx.x / 30;
    const int pos0 = pt * 16, c0 = ct * 32;
    const int t = threadIdx.x;
    {
        const int b = t / 16, pl = t % 16;
        const float4* src = (const float4*)(in + ((long)(b * 480 + pos0 + pl)) * 128 + c0);
        #pragma unroll
        for (int q = 0; q < 8; q++) {
            float4 v = src[q];
            tile_s[((4 * q + 0) * 16 + pl) * 17 + b] = v.x;
            tile_s[((4 * q + 1) * 16 + pl) * 17 + b] = v.y;
            tile_s[((4 * q + 2) * 16 + pl) * 17 + b] = v.z;
            tile_s[((4 * q + 3) * 16 + pl) * 17 + b] = v.w;
        }
    }
    __syncthreads();
    {
        const int w = t / 64, l = t % 64;
        const int pl2 = l / 4, b4 = l % 4;
        #pragma unroll
        for (int i = 0; i < 8; i++) {
            int cl = w + 4 * i;
            const float* ls = &tile_s[(cl * 16 + pl2) * 17 + 4 * b4];
            float4 v = make_float4(ls[0], ls[1], ls[2], ls[3]);
            *(float4*)(xT + ((long)(c0 + cl) * 480 + pos0 + pl2) * 16 + 4 * b4) = v;
        }
    }
}

// ---------------------------------------------------------------------------
// FC main v6 (R14): occupancy-first redesign.
// v3 counters (the first direct evidence): VGPR=84 (compiler REFUSED the
// w[30] preload -> loads re-sunk, serialized vmcnt chain), occupancy 20.7%
// (grid 512 + launch_bounds(,2) = 8 waves/CU), 683 GB/s, VALU 6%. All four
// variants were latency-bound at ~8 waves/CU: in-flight bytes/CU ~8 KB ~=
// the BW*latency product -> any scheduling slip falls off the BW roofline.
// v6 levers (each tied to a measured mechanism):
//  - grid 960 blocks (KB=64): 3.75 blocks/CU avg; VGPR budget <=128
//    (launch_bounds(256,4); acc 64 + 8 in-flight w + xv 16 + addr ~= 120)
//    -> 16 waves/CU (m69 cliff at 128). 2x the waves, 2x in flight.
//  - short load chains: per phase (32 k) only 8 independent float4 weight
//    loads/thread; 2 phases reuse the same registers.
//  - weight instr = 16 x 64 B full lines (4-lane group per line), each oc
//    row read as 2x128 B contiguous runs. Read-once 63 MB.
//  - x: 64x16 chunk in 5 KB LDS (read ONCE total, 3.9 MB); broadcast b128
//    reads (4 distinct addrs/instr, 2-way banks = free per m136/m122-v3);
//    64 b128/thread for 1024 FMAs = 16:1 (v3's 4:1 cost ~19 us LDS-pipe).
//  - partial 960x256x16 = 15.7 MB round-trip (~5 us) is the price of the
//    fine k-split; fc_reduce widened to 60-chunk sums.
// ---------------------------------------------------------------------------
__global__ __launch_bounds__(256, 4) void fc_main(const float* __restrict__ xT,
                                                  const float* __restrict__ fw,
                                                  float* __restrict__ partial)
{
    __shared__ float x_lds[64 * 20];           // 5120 B, row stride 20 floats
    const int kc   = blockIdx.x;               // 960 k-chunks of 64
    const int t    = threadIdx.x;
    const int q    = t >> 2;                   // oc group 0..63
    const int ksub = t & 3;
    const int k0   = kc * FC_KB;

    // ---- stage x[64][16] into LDS: one float4 per thread, coalesced ----
    {
        const int kr = t >> 2, b4 = t & 3;
        *(float4*)(&x_lds[kr * 20 + b4 * 4]) =
            *(const float4*)(xT + ((long)(k0 + kr)) * 16 + b4 * 4);
    }
    __syncthreads();

    float acc[4][16];
    #pragma unroll
    for (int s = 0; s < 4; s++)
        #pragma unroll
        for (int b = 0; b < 16; b++) acc[s][b] = 0.f;

    const float* wbase = fw + (long)q * FC_K + k0 + ksub * 4;

    #pragma unroll
    for (int p = 0; p < 2; p++) {
        // 8 independent weight loads (4 oc x 2 float4), issued together
        f32x4 w[4][2];
        #pragma unroll
        for (int s = 0; s < 4; s++) {
            const float* wr = wbase + (long)s * (64 * FC_K) + p * 32;
            w[s][0] = *(const f32x4*)(wr);
            w[s][1] = *(const f32x4*)(wr + 16);
        }
        #pragma unroll
        for (int f = 0; f < 2; f++) {
            #pragma unroll
            for (int e = 0; e < 4; e++) {
                const int row = p * 32 + f * 16 + ksub * 4 + e;
                const float* xr = &x_lds[row * 20];
                f32x4 xv[4];
                #pragma unroll
                for (int b4 = 0; b4 < 4; b4++)
                    xv[b4] = *(const f32x4*)(xr + 4 * b4);
                #pragma unroll
                for (int s = 0; s < 4; s++) {
                    const float wv = w[s][f][e];
                    #pragma unroll
                    for (int b4 = 0; b4 < 4; b4++)
                        #pragma unroll
                        for (int el = 0; el < 4; el++)
                            acc[s][b4 * 4 + el] = fmaf(wv, xv[b4][el], acc[s][b4 * 4 + el]);
                }
            }
        }
    }

    // ---- reduce over the 4-lane group (ksub) ----
    #pragma unroll
    for (int s = 0; s < 4; s++)
        #pragma unroll
        for (int b = 0; b < 16; b++) {
            float v = acc[s][b];
            v += __shfl_xor(v, 1);
            v += __shfl_xor(v, 2);
            acc[s][b] = v;
        }

    if (ksub == 0) {
        #pragma unroll
        for (int s = 0; s < 4; s++) {
            const int oc = q + 64 * s;
            float4* pp = (float4*)(partial + ((long)kc * 256 + oc) * 16);
            pp[0] = make_float4(acc[s][0],  acc[s][1],  acc[s][2],  acc[s][3]);
            pp[1] = make_float4(acc[s][4],  acc[s][5],  acc[s][6],  acc[s][7]);
            pp[2] = make_float4(acc[s][8],  acc[s][9],  acc[s][10], acc[s][11]);
            pp[3] = make_float4(acc[s][12], acc[s][13], acc[s][14], acc[s][15]);
        }
    }
}

// ---------------------------------------------------------------------------
// FC reduce: 256 blocks (one oc each) x 256 threads. Thread (b=t&15,
// stripe=t>>4) sums 60 chunks; 16x16 LDS tree finishes. 15.7 MB total read
// across 1024 waves -> ~3 us.
// ---------------------------------------------------------------------------
__global__ __launch_bounds__(256) void fc_reduce(const float* __restrict__ partial,
                                                 const float* __restrict__ fcb,
                                                 float* __restrict__ out)
{
    __shared__ float red[16][17];
    const int oc = blockIdx.x;             // 256
    const int ol = threadIdx.x & 15;       // b
    const int st = threadIdx.x >> 4;       // chunk stripe
    float s = 0.f;
    #pragma unroll 4
    for (int j = 0; j < 60; j++)           // kc = st + 16*j covers 0..959
        s += partial[(long)(st + 16 * j) * 4096 + oc * 16 + ol];
    red[st][ol] = s;
    __syncthreads();
    if (threadIdx.x < 16) {
        float tot = fcb[oc];
        #pragma unroll
        for (int k = 0; k < 16; k++) tot += red[k][threadIdx.x];
        out[threadIdx.x * 256 + oc] = fmaxf(tot, 0.f);   // out[b][oc]
    }
}

// ---------------------------------------------------------------------------
extern "C" void kernel_launch(void* const* d_in, const int* in_sizes, int n_in,
                              void* d_out, int out_size, void* d_ws, size_t ws_size,
                              hipStream_t stream) {
    const float* input  = (const float*)d_in[0];
    const int*   coords = (const int*)d_in[1];
    const float* w1 = (const float*)d_in[2];
    const float* b1 = (const float*)d_in[3];
    const float* w2 = (const float*)d_in[4];
    const float* b2 = (const float*)d_in[5];
    const float* w3 = (const float*)d_in[6];
    const float* b3 = (const float*)d_in[7];
    const float* fcw = (const float*)d_in[8];
    const float* fcb = (const float*)d_in[9];
    float* outp = (float*)d_out;

    const int n_active = in_sizes[1] / 3;

    // ---- workspace layout (~71 MB total) ----
    char* ws = (char*)d_ws;
    unsigned short* wf1 = (unsigned short*)ws;            // 18,432 B
    unsigned short* wf2 = wf1 + 9216;                     // 36,864 B
    unsigned short* wf3 = wf2 + 18432;                    // 147,456 B
    unsigned short* inBf = (unsigned short*)(ws + 204800);        // 31,457,280 B (16*96*320*32 bf16)
    char* regA = ws + 204800 + 31457280;                  // 15,728,640 B
    char* regB = regA + 15728640;                         // 7,864,320 B
    float* partial = (float*)(regB + 7864320);            // 15,728,640 B (960*256*16*4)

    // ping-pong aliasing (stream-ordered, each buffer dead before reuse):
    float*          conv1o  = (float*)regA;           // 15.73 MB fp32
    unsigned short* pool1bf = (unsigned short*)regB;   //  7.86 MB bf16
    float*          conv2o  = (float*)regA;           //  7.86 MB fp32
    unsigned short* pool2bf = (unsigned short*)regB;   //  3.93 MB bf16
    float*          conv3o  = (float*)regA;           //  3.93 MB fp32
    float*          pool3f  = (float*)regB;           //  3.93 MB fp32
    float*          xT      = (float*)regA;           //  3.93 MB fp32

    // zero dense bf16 input (31,457,280 B -- R7's bug was undersizing this),
    // then fused wfrag-prep + scatter-cast of active cells only.
    hipMemsetAsync(inBf, 0, 31457280, stream);
    const int scatterBlocks = (n_active * 4 + 255) / 256;
    setup_all<<<396 + scatterBlocks, 256, 0, stream>>>(w1, w2, w3, wf1, wf2, wf3,
                                                       coords, input, inBf, n_active);

    // conv1: (16,96,320,32)->(16,48,160,32); NT=2 NL=2 -> 7680 waves
    conv_mfma<32, 32, 2, 96, 320, 48, 160>
        <<<1920, 256, 0, stream>>>(inBf, wf1, b1, conv1o);
    maxpool3_relu<32, 48, 160, true><<<3840, 256, 0, stream>>>(conv1o, pool1bf);

    // conv2: (16,48,160,32)->(16,24,80,64); NT=4 NL=2 -> 3840 waves
    conv_mfma<32, 64, 2, 48, 160, 24, 80>
        <<<960, 256, 0, stream>>>(pool1bf, wf2, b2, conv2o);
    maxpool3_relu<64, 24, 80, true><<<1920, 256, 0, stream>>>(conv2o, pool2bf);

    // conv3: (16,24,80,64)->(16,12,40,128); NT=8 NL=2 -> 1920 waves
    conv_mfma<64, 128, 2, 24, 80, 12, 40>
        <<<480, 256, 0, stream>>>(pool2bf, wf3, b3, conv3o);
    maxpool3_relu<128, 12, 40, false><<<960, 256, 0, stream>>>(conv3o, pool3f);

    // flatten permute + FC (fp32, exact weights; read-once both streams)
    transpose_fc<<<120, 256, 0, stream>>>(pool3f, xT);
    fc_main<<<FC_NKC, 256, 0, stream>>>(xT, fcw, partial);
    fc_reduce<<<256, 256, 0, stream>>>(partial, fcb, outp);
}

// Round 5
// 245.426 us; speedup vs baseline: 1.0133x; 1.0133x over previous
//
#include <hip/hip_runtime.h>

// Problem constants
#define NB 16
#define NH 96
#define NW 320
#define NCIN 32

#define FC_K 61440
#define FC_KB 128          // k per block (2 phases x 64)
#define FC_NKC 480         // 61440/128 chunks; 480 blocks x 8 waves = 15 waves/CU

typedef __attribute__((ext_vector_type(8))) short short8;     // 8 bf16 (4 VGPRs)
typedef __attribute__((ext_vector_type(4))) float f32x4;

__device__ inline unsigned short f2bf(float f) {
    union { float f; unsigned int u; } v; v.f = f;
    unsigned int r = v.u + 0x7FFF + ((v.u >> 16) & 1);   // RNE
    return (unsigned short)(r >> 16);
}

// ---------------------------------------------------------------------------
// Fused setup kernel.
// Blocks [0,396): weight fragments OIHW fp32 -> MFMA B-operand bf16,
//   wf[((kk*NT + nt)*64 + lane)*8 + j], oc = nt*16+(lane&15),
//   ic = ks*32+(lane>>4)*8+j  [m91-verified map]
// Blocks [396,...): scatter+cast active cells from fp32 input into the
//   (memset-zeroed) dense bf16 input. Reads ONLY active cells (~25.6 MB).
//   4 threads per coord, 8 ch each; duplicates write identical bytes.
// ---------------------------------------------------------------------------
__global__ __launch_bounds__(256) void setup_all(const float* __restrict__ w1,
                                                 const float* __restrict__ w2,
                                                 const float* __restrict__ w3,
                                                 unsigned short* __restrict__ f1,
                                                 unsigned short* __restrict__ f2,
                                                 unsigned short* __restrict__ f3,
                                                 const int* __restrict__ coords,
                                                 const float* __restrict__ input,
                                                 unsigned short* __restrict__ inBf,
                                                 int n) {
    if (blockIdx.x < 396) {
        int i = blockIdx.x * 256 + threadIdx.x;
        if (i < 9216) {                       // conv1: IC=32 OC=32 NT=2 KS=1
            int j = i & 7, lane = (i >> 3) & 63, nt = (i >> 9) & 1, tap = i >> 10;
            int ic = ((lane >> 4) * 8) + j, oc = nt * 16 + (lane & 15);
            f1[i] = f2bf(w1[(oc * 32 + ic) * 9 + tap]);
        } else if (i < 27648) {               // conv2: IC=32 OC=64 NT=4 KS=1
            int v = i - 9216;
            int j = v & 7, lane = (v >> 3) & 63, nt = (v >> 9) & 3, tap = v >> 11;
            int ic = ((lane >> 4) * 8) + j, oc = nt * 16 + (lane & 15);
            f2[v] = f2bf(w2[(oc * 32 + ic) * 9 + tap]);
        } else if (i < 101376) {              // conv3: IC=64 OC=128 NT=8 KS=2
            int v = i - 27648;
            int j = v & 7, lane = (v >> 3) & 63, nt = (v >> 9) & 7, kk = v >> 12;
            int tap = kk >> 1, ks = kk & 1;
            int ic = ks * 32 + ((lane >> 4) * 8) + j, oc = nt * 16 + (lane & 15);
            f3[v] = f2bf(w3[(oc * 64 + ic) * 9 + tap]);
        }
    } else {
        int i = (blockIdx.x - 396) * 256 + threadIdx.x;
        if (i >= n * 4) return;
        int ci = i >> 2, q = i & 3;
        int b = coords[ci * 3 + 0], y = coords[ci * 3 + 1], x = coords[ci * 3 + 2];
        long base = ((long)((b * NH + y) * NW + x)) * NCIN + q * 8;
        const float4* src = (const float4*)(input + base);
        float4 v0 = src[0], v1 = src[1];
        union { short8 s8; unsigned short us[8]; } o;
        o.us[0] = f2bf(v0.x); o.us[1] = f2bf(v0.y); o.us[2] = f2bf(v0.z); o.us[3] = f2bf(v0.w);
        o.us[4] = f2bf(v1.x); o.us[5] = f2bf(v1.y); o.us[6] = f2bf(v1.z); o.us[7] = f2bf(v1.w);
        *(short8*)(inBf + base) = o.s8;
    }
}

// ---------------------------------------------------------------------------
// Implicit-GEMM conv 3x3 stride-2 pad-1 via bf16 MFMA (16x16x32), bf16 NHWC in.
// Each wave: one 16-position strip x NL oc-tiles. A-fragments loaded ONCE
// per ks (9 x 16 B/lane, unconditional, addr clamped to cell 0, reg-reg
// cndmask -- R8 lesson), reused for NL*9 MFMAs. B-frag loads coalesced
// 1KB/wave, L1-hot, in-loop. acc indices compile-time (R4), ks loop unroll 1
// (R2). Layouts m89/m91: A[m=lane&15][k=quad*8+j], D[row=quad*4+reg][col=lane&15].
// R14: NL is an occupancy lever -- conv3 runs NL=1 (960 blocks, 15 waves/CU)
// since its input is L2-hot and latency, not gather traffic, dominated.
// ---------------------------------------------------------------------------
template<int IC, int OC, int NL, int IH, int IW, int OH, int OW>
__global__ __launch_bounds__(256) void conv_mfma(
    const unsigned short* __restrict__ inPtr,  // NHWC bf16
    const unsigned short* __restrict__ wfrag,  // B-fragments bf16
    const float* __restrict__ bias,
    float* __restrict__ out)                   // NHWC fp32 (pre-relu)
{
    constexpr int KS = IC / 32;
    constexpr int NT = OC / 16;
    constexpr int NG = NT / NL;                // wave-groups per strip
    constexpr int NSTRIPS = NB * OH * OW / 16;

    const int wid  = (blockIdx.x * 256 + threadIdx.x) >> 6;
    const int lane = threadIdx.x & 63;
    const int ntb  = (wid % NG) * NL;
    const int s    = wid / NG;
    if (s >= NSTRIPS) return;
    const int quad = lane >> 4;
    const int lm   = lane & 15;

    const int p0 = s * 16;
    const int posA = p0 + lm;
    const int b  = posA / (OH * OW);
    const int rr = posA % (OH * OW);
    const int oy = rr / OW, ox = rr % OW;
    const int iy0 = oy * 2 - 1, ix0 = ox * 2 - 1;

    int cell[9];
    bool okb[9];
    #pragma unroll
    for (int t9 = 0; t9 < 9; t9++) {
        const int iy = iy0 + t9 / 3;
        const int ix = ix0 + t9 % 3;
        const bool ok = (iy >= 0) && (iy < IH) && (ix >= 0) && (ix < IW);
        cell[t9] = ok ? ((b * IH + iy) * IW + ix) : 0;   // clamp addr, not load
        okb[t9] = ok;
    }

    short8 zero8;
    #pragma unroll
    for (int j = 0; j < 8; j++) zero8[j] = 0;

    f32x4 acc[NL][2];
    #pragma unroll
    for (int nl = 0; nl < NL; nl++)
        #pragma unroll
        for (int pp = 0; pp < 2; pp++)
            acc[nl][pp] = (f32x4){0.f, 0.f, 0.f, 0.f};

    #pragma unroll 1
    for (int ks = 0; ks < KS; ks++) {
        short8 av[9];
        #pragma unroll
        for (int t9 = 0; t9 < 9; t9++) {
            short8 v = *(const short8*)(inPtr + (long)cell[t9] * IC + ks * 32 + quad * 8);
            av[t9] = okb[t9] ? v : zero8;      // reg-reg cndmask
        }
        #pragma unroll
        for (int nl = 0; nl < NL; nl++) {
            #pragma unroll
            for (int t9 = 0; t9 < 9; t9++) {
                short8 bf = *(const short8*)(wfrag + (((t9 * KS + ks) * NT + ntb + nl) * 64 + lane) * 8);
                if (t9 & 1) acc[nl][1] = __builtin_amdgcn_mfma_f32_16x16x32_bf16(av[t9], bf, acc[nl][1], 0, 0, 0);
                else        acc[nl][0] = __builtin_amdgcn_mfma_f32_16x16x32_bf16(av[t9], bf, acc[nl][0], 0, 0, 0);
            }
        }
    }

    const long rowBase = (long)p0 + quad * 4;   // D: row=(lane>>4)*4+reg
    #pragma unroll
    for (int nl = 0; nl < NL; nl++) {
        const int oc = (ntb + nl) * 16 + lm;
        const float bv = bias[oc];
        #pragma unroll
        for (int reg = 0; reg < 4; reg++)
            out[(rowBase + reg) * OC + oc] = acc[nl][0][reg] + acc[nl][1][reg] + bv;
    }
}

// ---------------------------------------------------------------------------
// 3x3 stride-1 pad-1 maxpool (-inf pad) + ReLU, NHWC. fp32 in; bf16 or fp32
// out (bf16 feeds the next conv's MFMA A-operand).
// ---------------------------------------------------------------------------
template<int C, int HH, int WW, bool BF16OUT>
__global__ __launch_bounds__(256) void maxpool3_relu(const float* __restrict__ in, void* __restrict__ outv) {
    constexpr int C4 = C / 4;
    int i = blockIdx.x * blockDim.x + threadIdx.x;
    if (i >= NB * HH * WW * C4) return;
    int c = i % C4;
    int x = (i / C4) % WW;
    int y = (i / (C4 * WW)) % HH;
    int b = i / (C4 * WW * HH);
    float4 m = make_float4(-3.0e38f, -3.0e38f, -3.0e38f, -3.0e38f);
    #pragma unroll
    for (int dy = -1; dy <= 1; dy++) {
        int yy = y + dy;
        if (yy < 0 || yy >= HH) continue;
        #pragma unroll
        for (int dx = -1; dx <= 1; dx++) {
            int xx = x + dx;
            if (xx < 0 || xx >= WW) continue;
            float4 v = ((const float4*)in)[((b * HH + yy) * WW + xx) * C4 + c];
            m.x = fmaxf(m.x, v.x);
            m.y = fmaxf(m.y, v.y);
            m.z = fmaxf(m.z, v.z);
            m.w = fmaxf(m.w, v.w);
        }
    }
    m.x = fmaxf(m.x, 0.f);
    m.y = fmaxf(m.y, 0.f);
    m.z = fmaxf(m.z, 0.f);
    m.w = fmaxf(m.w, 0.f);
    if (BF16OUT) {
        ushort4 o;
        o.x = f2bf(m.x); o.y = f2bf(m.y); o.z = f2bf(m.z); o.w = f2bf(m.w);
        ((ushort4*)outv)[i] = o;
    } else {
        ((float4*)outv)[i] = m;
    }
}

// ---------------------------------------------------------------------------
// LDS-tiled permute: in[b][pos][c] (NHWC pooled3 fp32, pos=480,c=128) ->
// xT[c*480+pos][b]. Both sides coalesced.
// R14: 120 -> 480 blocks (8-channel c-tiles). The old 120-block version was
// 0.47 blocks/CU -- half the GPU idle, the rest latency-bound at 2 waves/CU.
// ---------------------------------------------------------------------------
__global__ __launch_bounds__(256) void transpose_fc(const float* __restrict__ in, float* __restrict__ xT) {
    __shared__ float tile_s[8 * 16 * 17];     // [c_l][pos_l][b(pad 17)]
    const int pt = blockIdx.x % 30;
    const int ct = blockIdx.x / 30;           // 0..15
    const int pos0 = pt * 16, c0 = ct * 8;
    const int t = threadIdx.x;
    {
        const int b = t >> 4, pl = t & 15;
        const float4* src = (const float4*)(in + ((long)(b * 480 + pos0 + pl)) * 128 + c0);
        #pragma unroll
        for (int q = 0; q < 2; q++) {
            float4 v = src[q];
            tile_s[((4 * q + 0) * 16 + pl) * 17 + b] = v.x;
            tile_s[((4 * q + 1) * 16 + pl) * 17 + b] = v.y;
            tile_s[((4 * q + 2) * 16 + pl) * 17 + b] = v.z;
            tile_s[((4 * q + 3) * 16 + pl) * 17 + b] = v.w;
        }
    }
    __syncthreads();
    {
        const int w = t >> 6, l = t & 63;
        const int pl2 = l >> 2, b4 = l & 3;
        #pragma unroll
        for (int i = 0; i < 2; i++) {
            int cl = w + 4 * i;
            const float* ls = &tile_s[(cl * 16 + pl2) * 17 + 4 * b4];
            float4 v = make_float4(ls[0], ls[1], ls[2], ls[3]);
            *(float4*)(xT + ((long)(c0 + cl) * 480 + pos0 + pl2) * 16 + 4 * b4) = v;
        }
    }
}

// ---------------------------------------------------------------------------
// FC main v7 (R14): v6 structure (occupancy-first, 8 short weight loads per
// phase, 4-lane oc-groups = one 64 B line per instr, LDS-broadcast x) with
// KB 64->128 and 512-thread blocks (2 oc/thread): same 15 waves/CU but the
// partial round-trip halves (15.7 -> 7.9 MB). VGPR ~100 (acc 32 + w 32 +
// xv 16), launch_bounds(512,4) -> 16 waves/CU budget.
// ---------------------------------------------------------------------------
__global__ __launch_bounds__(512, 4) void fc_main(const float* __restrict__ xT,
                                                  const float* __restrict__ fw,
                                                  float* __restrict__ partial)
{
    __shared__ float x_lds[128 * 20];          // 10 KB, row stride 20 floats
    const int kc   = blockIdx.x;               // 480 k-chunks of 128
    const int t    = threadIdx.x;              // 512
    const int q    = t >> 2;                   // oc group 0..127
    const int ksub = t & 3;
    const int k0   = kc * FC_KB;

    // ---- stage x[128][16] into LDS: one float4 per thread, coalesced ----
    {
        const int kr = t >> 2, b4 = t & 3;     // kr 0..127
        *(float4*)(&x_lds[kr * 20 + b4 * 4]) =
            *(const float4*)(xT + ((long)(k0 + kr)) * 16 + b4 * 4);
    }
    __syncthreads();

    float acc[2][16];
    #pragma unroll
    for (int s = 0; s < 2; s++)
        #pragma unroll
        for (int b = 0; b < 16; b++) acc[s][b] = 0.f;

    const float* wbase = fw + (long)q * FC_K + k0 + ksub * 4;

    #pragma unroll
    for (int p = 0; p < 2; p++) {
        // 8 independent weight loads (2 oc x 4 float4), issued together.
        // 4-lane group covers one full 64 B line per load; 4 loads/oc walk a
        // contiguous 256 B run.
        f32x4 w[2][4];
        #pragma unroll
        for (int s = 0; s < 2; s++) {
            const float* wr = wbase + (long)s * (128 * FC_K) + p * 64;
            #pragma unroll
            for (int j = 0; j < 4; j++)
                w[s][j] = *(const f32x4*)(wr + j * 16);
        }
        #pragma unroll
        for (int j = 0; j < 4; j++) {
            #pragma unroll
            for (int e = 0; e < 4; e++) {
                const int row = p * 64 + j * 16 + ksub * 4 + e;
                const float* xr = &x_lds[row * 20];
                f32x4 xv[4];
                #pragma unroll
                for (int b4 = 0; b4 < 4; b4++)
                    xv[b4] = *(const f32x4*)(xr + 4 * b4);
                #pragma unroll
                for (int s = 0; s < 2; s++) {
                    const float wv = w[s][j][e];
                    #pragma unroll
                    for (int b4 = 0; b4 < 4; b4++)
                        #pragma unroll
                        for (int el = 0; el < 4; el++)
                            acc[s][b4 * 4 + el] = fmaf(wv, xv[b4][el], acc[s][b4 * 4 + el]);
                }
            }
        }
    }

    // ---- reduce over the 4-lane group (ksub) ----
    #pragma unroll
    for (int s = 0; s < 2; s++)
        #pragma unroll
        for (int b = 0; b < 16; b++) {
            float v = acc[s][b];
            v += __shfl_xor(v, 1);
            v += __shfl_xor(v, 2);
            acc[s][b] = v;
        }

    if (ksub == 0) {
        #pragma unroll
        for (int s = 0; s < 2; s++) {
            const int oc = q + 128 * s;
            float4* pp = (float4*)(partial + ((long)kc * 256 + oc) * 16);
            pp[0] = make_float4(acc[s][0],  acc[s][1],  acc[s][2],  acc[s][3]);
            pp[1] = make_float4(acc[s][4],  acc[s][5],  acc[s][6],  acc[s][7]);
            pp[2] = make_float4(acc[s][8],  acc[s][9],  acc[s][10], acc[s][11]);
            pp[3] = make_float4(acc[s][12], acc[s][13], acc[s][14], acc[s][15]);
        }
    }
}

// ---------------------------------------------------------------------------
// FC reduce: 256 blocks (one oc each) x 256 threads. Thread (b=t&15,
// stripe=t>>4) sums 30 chunks; 16x16 LDS tree finishes. 7.9 MB total read.
// ---------------------------------------------------------------------------
__global__ __launch_bounds__(256) void fc_reduce(const float* __restrict__ partial,
                                                 const float* __restrict__ fcb,
                                                 float* __restrict__ out)
{
    __shared__ float red[16][17];
    const int oc = blockIdx.x;             // 256
    const int ol = threadIdx.x & 15;       // b
    const int st = threadIdx.x >> 4;       // chunk stripe
    float s = 0.f;
    #pragma unroll 5
    for (int j = 0; j < 30; j++)           // kc = st + 16*j covers 0..479
        s += partial[(long)(st + 16 * j) * 4096 + oc * 16 + ol];
    red[st][ol] = s;
    __syncthreads();
    if (threadIdx.x < 16) {
        float tot = fcb[oc];
        #pragma unroll
        for (int k = 0; k < 16; k++) tot += red[k][threadIdx.x];
        out[threadIdx.x * 256 + oc] = fmaxf(tot, 0.f);   // out[b][oc]
    }
}

// ---------------------------------------------------------------------------
extern "C" void kernel_launch(void* const* d_in, const int* in_sizes, int n_in,
                              void* d_out, int out_size, void* d_ws, size_t ws_size,
                              hipStream_t stream) {
    const float* input  = (const float*)d_in[0];
    const int*   coords = (const int*)d_in[1];
    const float* w1 = (const float*)d_in[2];
    const float* b1 = (const float*)d_in[3];
    const float* w2 = (const float*)d_in[4];
    const float* b2 = (const float*)d_in[5];
    const float* w3 = (const float*)d_in[6];
    const float* b3 = (const float*)d_in[7];
    const float* fcw = (const float*)d_in[8];
    const float* fcb = (const float*)d_in[9];
    float* outp = (float*)d_out;

    const int n_active = in_sizes[1] / 3;

    // ---- workspace layout (~63 MB total) ----
    char* ws = (char*)d_ws;
    unsigned short* wf1 = (unsigned short*)ws;            // 18,432 B
    unsigned short* wf2 = wf1 + 9216;                     // 36,864 B
    unsigned short* wf3 = wf2 + 18432;                    // 147,456 B
    unsigned short* inBf = (unsigned short*)(ws + 204800);        // 31,457,280 B (16*96*320*32 bf16)
    char* regA = ws + 204800 + 31457280;                  // 15,728,640 B
    char* regB = regA + 15728640;                         // 7,864,320 B
    float* partial = (float*)(regB + 7864320);            // 7,864,320 B (480*256*16*4)

    // ping-pong aliasing (stream-ordered, each buffer dead before reuse):
    float*          conv1o  = (float*)regA;           // 15.73 MB fp32
    unsigned short* pool1bf = (unsigned short*)regB;   //  7.86 MB bf16
    float*          conv2o  = (float*)regA;           //  7.86 MB fp32
    unsigned short* pool2bf = (unsigned short*)regB;   //  3.93 MB bf16
    float*          conv3o  = (float*)regA;           //  3.93 MB fp32
    float*          pool3f  = (float*)regB;           //  3.93 MB fp32
    float*          xT      = (float*)regA;           //  3.93 MB fp32

    // zero dense bf16 input (31,457,280 B -- R7's bug was undersizing this),
    // then fused wfrag-prep + scatter-cast of active cells only.
    hipMemsetAsync(inBf, 0, 31457280, stream);
    const int scatterBlocks = (n_active * 4 + 255) / 256;
    setup_all<<<396 + scatterBlocks, 256, 0, stream>>>(w1, w2, w3, wf1, wf2, wf3,
                                                       coords, input, inBf, n_active);

    // conv1: (16,96,320,32)->(16,48,160,32); NT=2 NL=2 -> 7680 waves
    conv_mfma<32, 32, 2, 96, 320, 48, 160>
        <<<1920, 256, 0, stream>>>(inBf, wf1, b1, conv1o);
    maxpool3_relu<32, 48, 160, true><<<3840, 256, 0, stream>>>(conv1o, pool1bf);

    // conv2: (16,48,160,32)->(16,24,80,64); NT=4 NL=2 -> 3840 waves
    conv_mfma<32, 64, 2, 48, 160, 24, 80>
        <<<960, 256, 0, stream>>>(pool1bf, wf2, b2, conv2o);
    maxpool3_relu<64, 24, 80, true><<<1920, 256, 0, stream>>>(conv2o, pool2bf);

    // conv3: (16,24,80,64)->(16,12,40,128); NT=8 NL=1 -> 3840 waves, 15/CU
    conv_mfma<64, 128, 1, 24, 80, 12, 40>
        <<<960, 256, 0, stream>>>(pool2bf, wf3, b3, conv3o);
    maxpool3_relu<128, 12, 40, false><<<960, 256, 0, stream>>>(conv3o, pool3f);

    // flatten permute (480 blocks) + FC (fp32, exact weights)
    transpose_fc<<<480, 256, 0, stream>>>(pool3f, xT);
    fc_main<<<FC_NKC, 512, 0, stream>>>(xT, fcw, partial);
    fc_reduce<<<256, 256, 0, stream>>>(partial, fcb, outp);
}

// Round 6
// 231.394 us; speedup vs baseline: 1.0747x; 1.0606x over previous
//
#include <hip/hip_runtime.h>

// Problem constants
#define NB 16
#define NH 96
#define NW 320
#define NCIN 32

#define FC_K 61440
#define FC_KB 128          // k per block (2 phases x 64)
#define FC_NKC 480         // 61440/128 chunks

typedef __attribute__((ext_vector_type(8))) short short8;     // 8 bf16 (4 VGPRs)
typedef __attribute__((ext_vector_type(4))) float f32x4;

__device__ inline unsigned short f2bf(float f) {
    union { float f; unsigned int u; } v; v.f = f;
    unsigned int r = v.u + 0x7FFF + ((v.u >> 16) & 1);   // RNE
    return (unsigned short)(r >> 16);
}
__device__ inline float bf2f(unsigned short s) {
    union { unsigned int u; float f; } v; v.u = ((unsigned int)s) << 16; return v.f;
}
__device__ inline unsigned short fhi(float f) {        // exact for bf16-valued floats
    union { float f; unsigned int u; } v; v.f = f; return (unsigned short)(v.u >> 16);
}

// ---------------------------------------------------------------------------
// Fused setup kernel (unchanged): wfrag prep + scatter-cast of active cells.
// ---------------------------------------------------------------------------
__global__ __launch_bounds__(256) void setup_all(const float* __restrict__ w1,
                                                 const float* __restrict__ w2,
                                                 const float* __restrict__ w3,
                                                 unsigned short* __restrict__ f1,
                                                 unsigned short* __restrict__ f2,
                                                 unsigned short* __restrict__ f3,
                                                 const int* __restrict__ coords,
                                                 const float* __restrict__ input,
                                                 unsigned short* __restrict__ inBf,
                                                 int n) {
    if (blockIdx.x < 396) {
        int i = blockIdx.x * 256 + threadIdx.x;
        if (i < 9216) {                       // conv1: IC=32 OC=32 NT=2 KS=1
            int j = i & 7, lane = (i >> 3) & 63, nt = (i >> 9) & 1, tap = i >> 10;
            int ic = ((lane >> 4) * 8) + j, oc = nt * 16 + (lane & 15);
            f1[i] = f2bf(w1[(oc * 32 + ic) * 9 + tap]);
        } else if (i < 27648) {               // conv2: IC=32 OC=64 NT=4 KS=1
            int v = i - 9216;
            int j = v & 7, lane = (v >> 3) & 63, nt = (v >> 9) & 3, tap = v >> 11;
            int ic = ((lane >> 4) * 8) + j, oc = nt * 16 + (lane & 15);
            f2[v] = f2bf(w2[(oc * 32 + ic) * 9 + tap]);
        } else if (i < 101376) {              // conv3: IC=64 OC=128 NT=8 KS=2
            int v = i - 27648;
            int j = v & 7, lane = (v >> 3) & 63, nt = (v >> 9) & 7, kk = v >> 12;
            int tap = kk >> 1, ks = kk & 1;
            int ic = ks * 32 + ((lane >> 4) * 8) + j, oc = nt * 16 + (lane & 15);
            f3[v] = f2bf(w3[(oc * 64 + ic) * 9 + tap]);
        }
    } else {
        int i = (blockIdx.x - 396) * 256 + threadIdx.x;
        if (i >= n * 4) return;
        int ci = i >> 2, q = i & 3;
        int b = coords[ci * 3 + 0], y = coords[ci * 3 + 1], x = coords[ci * 3 + 2];
        long base = ((long)((b * NH + y) * NW + x)) * NCIN + q * 8;
        const float4* src = (const float4*)(input + base);
        float4 v0 = src[0], v1 = src[1];
        union { short8 s8; unsigned short us[8]; } o;
        o.us[0] = f2bf(v0.x); o.us[1] = f2bf(v0.y); o.us[2] = f2bf(v0.z); o.us[3] = f2bf(v0.w);
        o.us[4] = f2bf(v1.x); o.us[5] = f2bf(v1.y); o.us[6] = f2bf(v1.z); o.us[7] = f2bf(v1.w);
        *(short8*)(inBf + base) = o.s8;
    }
}

// ---------------------------------------------------------------------------
// R15 FUSED conv(3x3 s2 p1, MFMA) + maxpool3(s1 p1) + relu, bf16 out.
// Rationale: 5 rounds of sub-kernel tuning left the total pinned at ~245 us
// while the fc/transpose "wins" summed to ~35 us -- the timeline is
// dispatch-overhead + intermediate round-trips spread over 12 sub-40us
// kernels. Fusing eliminates the fp32 conv intermediates entirely.
// Block: pooled tile TY x TX at (b, y0, x0), oc slice [ocsel*OCB, +OCB).
// Phase 1: conv of the (TY+2)x(TX+2) halo into LDS as bf16 (EXACT vs old
//   pipeline: RNE bf16 is monotone => bf16/max/relu commute).
//   Strips of 16 halo cells; wave = strip x NTB oc-tiles; A-gather 9x16B
//   clamped (R8), D: row=quad*4+reg (cell), col=lm (oc) [m89/m91].
// Phase 2: pool from LDS (cell stride OCB+8 ushorts kills the 8-way bank
//   pattern), relu via m=0 init, bf16 repack is a shift (values bf16-exact).
// Recompute ratio (TY+2)(TX+2)/(TY*TX) = 1.27-1.4x; conv MFMA is ~2us total.
// ---------------------------------------------------------------------------
template<int IC, int OC, int NTB, int TY, int TX, int IH, int IW, int OH, int OW>
__global__ __launch_bounds__(512) void convpool_mfma(
    const unsigned short* __restrict__ inPtr,  // NHWC bf16
    const unsigned short* __restrict__ wfrag,  // B-fragments bf16 (NT total tiles)
    const float* __restrict__ bias,
    unsigned short* __restrict__ outBf)        // pooled NHWC bf16
{
    constexpr int KS  = IC / 32;
    constexpr int NT  = OC / 16;               // total oc-tiles in wfrag
    constexpr int OCB = NTB * 16;              // oc per block
    constexpr int NOC = OC / OCB;
    constexpr int CY = TY + 2, CX = TX + 2;
    constexpr int NCELL  = CY * CX;
    constexpr int NSTRIP = (NCELL + 15) / 16;
    constexpr int CSS = OCB + 8;               // LDS cell stride (ushorts)
    constexpr int NTY = OH / TY, NTX = OW / TX;

    __shared__ __align__(16) unsigned short cs[NCELL * CSS];

    int bid = blockIdx.x;
    const int ocsel = bid % NOC; bid /= NOC;
    const int txi = bid % NTX;   bid /= NTX;
    const int tyi = bid % NTY;
    const int b   = bid / NTY;
    const int y0 = tyi * TY, x0 = txi * TX;

    const int t = threadIdx.x;
    const int wid = t >> 6, lane = t & 63, quad = lane >> 4, lm = lane & 15;

    short8 zero8;
    #pragma unroll
    for (int j = 0; j < 8; j++) zero8[j] = 0;

    // ---------------- phase 1: conv halo -> LDS bf16 ----------------
    for (int s = wid; s < NSTRIP; s += 8) {
        int idx = s * 16 + lm;
        if (idx > NCELL - 1) idx = NCELL - 1;          // clamp dummy lanes
        const int oy = y0 - 1 + idx / CX;
        const int ox = x0 - 1 + idx % CX;
        const int iy0 = oy * 2 - 1, ix0 = ox * 2 - 1;

        int cell[9]; bool okb[9];
        #pragma unroll
        for (int t9 = 0; t9 < 9; t9++) {
            const int iy = iy0 + t9 / 3;
            const int ix = ix0 + t9 % 3;
            const bool ok = (iy >= 0) && (iy < IH) && (ix >= 0) && (ix < IW);
            cell[t9] = ok ? ((b * IH + iy) * IW + ix) : 0;
            okb[t9] = ok;
        }

        f32x4 acc[NTB][2];
        #pragma unroll
        for (int nl = 0; nl < NTB; nl++)
            #pragma unroll
            for (int pp = 0; pp < 2; pp++)
                acc[nl][pp] = (f32x4){0.f, 0.f, 0.f, 0.f};

        #pragma unroll
        for (int ks = 0; ks < KS; ks++) {
            short8 av[9];
            #pragma unroll
            for (int t9 = 0; t9 < 9; t9++) {
                short8 v = *(const short8*)(inPtr + (long)cell[t9] * IC + ks * 32 + quad * 8);
                av[t9] = okb[t9] ? v : zero8;
            }
            #pragma unroll
            for (int nl = 0; nl < NTB; nl++) {
                const int nt = ocsel * NTB + nl;
                #pragma unroll
                for (int t9 = 0; t9 < 9; t9++) {
                    short8 bf = *(const short8*)(wfrag + (((t9 * KS + ks) * NT + nt) * 64 + lane) * 8);
                    if (t9 & 1) acc[nl][1] = __builtin_amdgcn_mfma_f32_16x16x32_bf16(av[t9], bf, acc[nl][1], 0, 0, 0);
                    else        acc[nl][0] = __builtin_amdgcn_mfma_f32_16x16x32_bf16(av[t9], bf, acc[nl][0], 0, 0, 0);
                }
            }
        }

        // D-store to LDS: lane holds rows quad*4+reg, col lm
        #pragma unroll
        for (int nl = 0; nl < NTB; nl++) {
            const float bv = bias[(ocsel * NTB + nl) * 16 + lm];
            #pragma unroll
            for (int reg = 0; reg < 4; reg++) {
                const int ci = s * 16 + quad * 4 + reg;
                if (ci < NCELL)
                    cs[ci * CSS + nl * 16 + lm] = f2bf(acc[nl][0][reg] + acc[nl][1][reg] + bv);
            }
        }
    }
    __syncthreads();

    // ---------------- phase 2: pool 3x3 s1 p1 + relu -> global bf16 ----------------
    constexpr int NTASK = TY * TX * (OCB / 8);
    for (int u = t; u < NTASK; u += 512) {
        const int c8 = u & (OCB / 8 - 1);
        const int px = (u / (OCB / 8)) % TX;
        const int py = u / ((OCB / 8) * TX);
        const int gy = y0 + py, gx = x0 + px;

        float m[8];
        #pragma unroll
        for (int e = 0; e < 8; e++) m[e] = 0.f;        // relu floor

        #pragma unroll
        for (int dy = -1; dy <= 1; dy++) {
            const int yy = gy + dy;
            if (yy < 0 || yy >= OH) continue;
            #pragma unroll
            for (int dx = -1; dx <= 1; dx++) {
                const int xx = gx + dx;
                if (xx < 0 || xx >= OW) continue;
                const int ci = (py + dy + 1) * CX + (px + dx + 1);
                short8 v = *(const short8*)(&cs[ci * CSS + c8 * 8]);
                #pragma unroll
                for (int e = 0; e < 8; e++)
                    m[e] = fmaxf(m[e], bf2f((unsigned short)v[e]));
            }
        }
        union { short8 s8; unsigned short us[8]; } o;
        #pragma unroll
        for (int e = 0; e < 8; e++) o.us[e] = fhi(m[e]);   // exact repack
        *(short8*)(outBf + ((long)((b * OH + gy) * OW + gx)) * OC + ocsel * OCB + c8 * 8) = o.s8;
    }
}

// ---------------------------------------------------------------------------
// Implicit-GEMM conv (unfused; used for conv3 only). Unchanged from R5.
// ---------------------------------------------------------------------------
template<int IC, int OC, int NL, int IH, int IW, int OH, int OW>
__global__ __launch_bounds__(256) void conv_mfma(
    const unsigned short* __restrict__ inPtr,
    const unsigned short* __restrict__ wfrag,
    const float* __restrict__ bias,
    float* __restrict__ out)
{
    constexpr int KS = IC / 32;
    constexpr int NT = OC / 16;
    constexpr int NG = NT / NL;
    constexpr int NSTRIPS = NB * OH * OW / 16;

    const int wid  = (blockIdx.x * 256 + threadIdx.x) >> 6;
    const int lane = threadIdx.x & 63;
    const int ntb  = (wid % NG) * NL;
    const int s    = wid / NG;
    if (s >= NSTRIPS) return;
    const int quad = lane >> 4;
    const int lm   = lane & 15;

    const int p0 = s * 16;
    const int posA = p0 + lm;
    const int b  = posA / (OH * OW);
    const int rr = posA % (OH * OW);
    const int oy = rr / OW, ox = rr % OW;
    const int iy0 = oy * 2 - 1, ix0 = ox * 2 - 1;

    int cell[9];
    bool okb[9];
    #pragma unroll
    for (int t9 = 0; t9 < 9; t9++) {
        const int iy = iy0 + t9 / 3;
        const int ix = ix0 + t9 % 3;
        const bool ok = (iy >= 0) && (iy < IH) && (ix >= 0) && (ix < IW);
        cell[t9] = ok ? ((b * IH + iy) * IW + ix) : 0;
        okb[t9] = ok;
    }

    short8 zero8;
    #pragma unroll
    for (int j = 0; j < 8; j++) zero8[j] = 0;

    f32x4 acc[NL][2];
    #pragma unroll
    for (int nl = 0; nl < NL; nl++)
        #pragma unroll
        for (int pp = 0; pp < 2; pp++)
            acc[nl][pp] = (f32x4){0.f, 0.f, 0.f, 0.f};

    #pragma unroll 1
    for (int ks = 0; ks < KS; ks++) {
        short8 av[9];
        #pragma unroll
        for (int t9 = 0; t9 < 9; t9++) {
            short8 v = *(const short8*)(inPtr + (long)cell[t9] * IC + ks * 32 + quad * 8);
            av[t9] = okb[t9] ? v : zero8;
        }
        #pragma unroll
        for (int nl = 0; nl < NL; nl++) {
            #pragma unroll
            for (int t9 = 0; t9 < 9; t9++) {
                short8 bf = *(const short8*)(wfrag + (((t9 * KS + ks) * NT + ntb + nl) * 64 + lane) * 8);
                if (t9 & 1) acc[nl][1] = __builtin_amdgcn_mfma_f32_16x16x32_bf16(av[t9], bf, acc[nl][1], 0, 0, 0);
                else        acc[nl][0] = __builtin_amdgcn_mfma_f32_16x16x32_bf16(av[t9], bf, acc[nl][0], 0, 0, 0);
            }
        }
    }

    const long rowBase = (long)p0 + quad * 4;
    #pragma unroll
    for (int nl = 0; nl < NL; nl++) {
        const int oc = (ntb + nl) * 16 + lm;
        const float bv = bias[oc];
        #pragma unroll
        for (int reg = 0; reg < 4; reg++)
            out[(rowBase + reg) * OC + oc] = acc[nl][0][reg] + acc[nl][1][reg] + bv;
    }
}

// ---------------------------------------------------------------------------
// R15 FUSED maxpool3+relu (fp32 exact) + transpose for the FC.
// Pool computed on the fly from L2-resident conv3o (3.9 MB); pooled values
// go through the same LDS tile as the old transpose and land in xT.
// Eliminates pool3f round-trip + one dispatch. 480 blocks.
// ---------------------------------------------------------------------------
__global__ __launch_bounds__(256) void pool_transpose(const float* __restrict__ conv3o,
                                                      float* __restrict__ xT) {
    __shared__ float tile_s[8 * 16 * 17];     // [c_l][pos_l][b(pad 17)]
    const int pt = blockIdx.x % 30;
    const int ct = blockIdx.x / 30;           // 0..15
    const int pos0 = pt * 16, c0 = ct * 8;
    const int t = threadIdx.x;
    {
        const int b = t >> 4, pl = t & 15;
        const int pos = pos0 + pl;
        const int py = pos / 40, px = pos % 40;
        float4 m0 = make_float4(0.f, 0.f, 0.f, 0.f);   // relu floor
        float4 m1 = make_float4(0.f, 0.f, 0.f, 0.f);
        #pragma unroll
        for (int dy = -1; dy <= 1; dy++) {
            const int yy = py + dy;
            if (yy < 0 || yy >= 12) continue;
            #pragma unroll
            for (int dx = -1; dx <= 1; dx++) {
                const int xx = px + dx;
                if (xx < 0 || xx >= 40) continue;
                const float4* src = (const float4*)(conv3o + ((long)((b * 12 + yy) * 40 + xx)) * 128 + c0);
                float4 v0 = src[0], v1 = src[1];
                m0.x = fmaxf(m0.x, v0.x); m0.y = fmaxf(m0.y, v0.y);
                m0.z = fmaxf(m0.z, v0.z); m0.w = fmaxf(m0.w, v0.w);
                m1.x = fmaxf(m1.x, v1.x); m1.y = fmaxf(m1.y, v1.y);
                m1.z = fmaxf(m1.z, v1.z); m1.w = fmaxf(m1.w, v1.w);
            }
        }
        tile_s[(0 * 16 + pl) * 17 + b] = m0.x;
        tile_s[(1 * 16 + pl) * 17 + b] = m0.y;
        tile_s[(2 * 16 + pl) * 17 + b] = m0.z;
        tile_s[(3 * 16 + pl) * 17 + b] = m0.w;
        tile_s[(4 * 16 + pl) * 17 + b] = m1.x;
        tile_s[(5 * 16 + pl) * 17 + b] = m1.y;
        tile_s[(6 * 16 + pl) * 17 + b] = m1.z;
        tile_s[(7 * 16 + pl) * 17 + b] = m1.w;
    }
    __syncthreads();
    {
        const int w = t >> 6, l = t & 63;
        const int pl2 = l >> 2, b4 = l & 3;
        #pragma unroll
        for (int i = 0; i < 2; i++) {
            int cl = w + 4 * i;
            const float* ls = &tile_s[(cl * 16 + pl2) * 17 + 4 * b4];
            float4 v = make_float4(ls[0], ls[1], ls[2], ls[3]);
            *(float4*)(xT + ((long)(c0 + cl) * 480 + pos0 + pl2) * 16 + 4 * b4) = v;
        }
    }
}

// ---------------------------------------------------------------------------
// FC main v7 (unchanged from R5).
// ---------------------------------------------------------------------------
__global__ __launch_bounds__(512, 4) void fc_main(const float* __restrict__ xT,
                                                  const float* __restrict__ fw,
                                                  float* __restrict__ partial)
{
    __shared__ float x_lds[128 * 20];
    const int kc   = blockIdx.x;
    const int t    = threadIdx.x;
    const int q    = t >> 2;
    const int ksub = t & 3;
    const int k0   = kc * FC_KB;

    {
        const int kr = t >> 2, b4 = t & 3;
        *(float4*)(&x_lds[kr * 20 + b4 * 4]) =
            *(const float4*)(xT + ((long)(k0 + kr)) * 16 + b4 * 4);
    }
    __syncthreads();

    float acc[2][16];
    #pragma unroll
    for (int s = 0; s < 2; s++)
        #pragma unroll
        for (int b = 0; b < 16; b++) acc[s][b] = 0.f;

    const float* wbase = fw + (long)q * FC_K + k0 + ksub * 4;

    #pragma unroll
    for (int p = 0; p < 2; p++) {
        f32x4 w[2][4];
        #pragma unroll
        for (int s = 0; s < 2; s++) {
            const float* wr = wbase + (long)s * (128 * FC_K) + p * 64;
            #pragma unroll
            for (int j = 0; j < 4; j++)
                w[s][j] = *(const f32x4*)(wr + j * 16);
        }
        #pragma unroll
        for (int j = 0; j < 4; j++) {
            #pragma unroll
            for (int e = 0; e < 4; e++) {
                const int row = p * 64 + j * 16 + ksub * 4 + e;
                const float* xr = &x_lds[row * 20];
                f32x4 xv[4];
                #pragma unroll
                for (int b4 = 0; b4 < 4; b4++)
                    xv[b4] = *(const f32x4*)(xr + 4 * b4);
                #pragma unroll
                for (int s = 0; s < 2; s++) {
                    const float wv = w[s][j][e];
                    #pragma unroll
                    for (int b4 = 0; b4 < 4; b4++)
                        #pragma unroll
                        for (int el = 0; el < 4; el++)
                            acc[s][b4 * 4 + el] = fmaf(wv, xv[b4][el], acc[s][b4 * 4 + el]);
                }
            }
        }
    }

    #pragma unroll
    for (int s = 0; s < 2; s++)
        #pragma unroll
        for (int b = 0; b < 16; b++) {
            float v = acc[s][b];
            v += __shfl_xor(v, 1);
            v += __shfl_xor(v, 2);
            acc[s][b] = v;
        }

    if (ksub == 0) {
        #pragma unroll
        for (int s = 0; s < 2; s++) {
            const int oc = q + 128 * s;
            float4* pp = (float4*)(partial + ((long)kc * 256 + oc) * 16);
            pp[0] = make_float4(acc[s][0],  acc[s][1],  acc[s][2],  acc[s][3]);
            pp[1] = make_float4(acc[s][4],  acc[s][5],  acc[s][6],  acc[s][7]);
            pp[2] = make_float4(acc[s][8],  acc[s][9],  acc[s][10], acc[s][11]);
            pp[3] = make_float4(acc[s][12], acc[s][13], acc[s][14], acc[s][15]);
        }
    }
}

__global__ __launch_bounds__(256) void fc_reduce(const float* __restrict__ partial,
                                                 const float* __restrict__ fcb,
                                                 float* __restrict__ out)
{
    __shared__ float red[16][17];
    const int oc = blockIdx.x;
    const int ol = threadIdx.x & 15;
    const int st = threadIdx.x >> 4;
    float s = 0.f;
    #pragma unroll 5
    for (int j = 0; j < 30; j++)
        s += partial[(long)(st + 16 * j) * 4096 + oc * 16 + ol];
    red[st][ol] = s;
    __syncthreads();
    if (threadIdx.x < 16) {
        float tot = fcb[oc];
        #pragma unroll
        for (int k = 0; k < 16; k++) tot += red[k][threadIdx.x];
        out[threadIdx.x * 256 + oc] = fmaxf(tot, 0.f);
    }
}

// ---------------------------------------------------------------------------
extern "C" void kernel_launch(void* const* d_in, const int* in_sizes, int n_in,
                              void* d_out, int out_size, void* d_ws, size_t ws_size,
                              hipStream_t stream) {
    const float* input  = (const float*)d_in[0];
    const int*   coords = (const int*)d_in[1];
    const float* w1 = (const float*)d_in[2];
    const float* b1 = (const float*)d_in[3];
    const float* w2 = (const float*)d_in[4];
    const float* b2 = (const float*)d_in[5];
    const float* w3 = (const float*)d_in[6];
    const float* b3 = (const float*)d_in[7];
    const float* fcw = (const float*)d_in[8];
    const float* fcb = (const float*)d_in[9];
    float* outp = (float*)d_out;

    const int n_active = in_sizes[1] / 3;

    // ---- workspace layout (~59 MB, no aliasing) ----
    char* ws = (char*)d_ws;
    unsigned short* wf1 = (unsigned short*)ws;                    // 18,432 B
    unsigned short* wf2 = wf1 + 9216;                             // 36,864 B
    unsigned short* wf3 = wf2 + 18432;                            // 147,456 B
    unsigned short* inBf    = (unsigned short*)(ws + 204800);     // 31,457,280 B
    unsigned short* pool1bf = (unsigned short*)(ws + 31662080);   //  7,864,320 B (16*48*160*32 bf16)
    unsigned short* pool2bf = (unsigned short*)(ws + 39526400);   //  3,932,160 B (16*24*80*64 bf16)
    float*          conv3o  = (float*)(ws + 43458560);            //  3,932,160 B (16*12*40*128 f32)
    float*          xT      = (float*)(ws + 47390720);            //  3,932,160 B
    float*          partial = (float*)(ws + 51322880);            //  7,864,320 B (480*256*16*4)

    // zero dense bf16 input, then fused wfrag-prep + scatter-cast.
    hipMemsetAsync(inBf, 0, 31457280, stream);
    const int scatterBlocks = (n_active * 4 + 255) / 256;
    setup_all<<<396 + scatterBlocks, 256, 0, stream>>>(w1, w2, w3, wf1, wf2, wf3,
                                                       coords, input, inBf, n_active);

    // conv1+pool1 fused: (16,96,320,32)->(16,48,160,32) bf16
    // tile 16x16, halo 18x18, OCB=32 -> grid 16*3*10 = 480, 8 waves
    convpool_mfma<32, 32, 2, 16, 16, 96, 320, 48, 160>
        <<<480, 512, 0, stream>>>(inBf, wf1, b1, pool1bf);

    // conv2+pool2 fused: (16,48,160,32)->(16,24,80,64) bf16
    // tile 8x16, halo 10x18, OCB=32 (2 oc slices) -> grid 16*3*5*2 = 480
    convpool_mfma<32, 64, 2, 8, 16, 48, 160, 24, 80>
        <<<480, 512, 0, stream>>>(pool1bf, wf2, b2, pool2bf);

    // conv3 (unfused, fp32 out): (16,24,80,64)->(16,12,40,128); NL=1, 960 blocks
    conv_mfma<64, 128, 1, 24, 80, 12, 40>
        <<<960, 256, 0, stream>>>(pool2bf, wf3, b3, conv3o);

    // pool3+transpose fused (fp32 exact) -> xT
    pool_transpose<<<480, 256, 0, stream>>>(conv3o, xT);

    // FC
    fc_main<<<FC_NKC, 512, 0, stream>>>(xT, fcw, partial);
    fc_reduce<<<256, 256, 0, stream>>>(partial, fcb, outp);
}